// Round 1
// baseline (343.986 us; speedup 1.0000x reference)
//
#include <hip/hip_runtime.h>
#include <hip/hip_bf16.h>

// Transformer block fwd: B=2, T=2048, C=1024, H=16, D=64.
// out = concat(x_out fp32 [2,2048,1024], k fp32 [2,16,2048,64], v fp32 [2,16,2048,64])

#define T_SEQ 2048
#define C_DIM 1024
#define HEADS 16
#define HD    64

typedef __attribute__((ext_vector_type(8))) short s16x8;   // 8 x bf16 (4 VGPR) — MFMA A/B frag
typedef __attribute__((ext_vector_type(4))) short s16x4;
typedef __attribute__((ext_vector_type(4))) float f32x4;   // MFMA C/D frag

__device__ __forceinline__ short f2bf(float f) {
    union { __hip_bfloat16 h; short s; } u;
    u.h = __float2bfloat16(f);
    return u.s;
}

// ---------------- weight transpose + cast: W[K][N] fp32 -> Wt[N][K] bf16 ----------------
__global__ __launch_bounds__(256) void transpose_cast_kernel(
    const float* __restrict__ W, short* __restrict__ Wt, int K, int N) {
    __shared__ float t[32][33];
    int n0 = blockIdx.x * 32, k0 = blockIdx.y * 32;
    int tx = threadIdx.x, ty = threadIdx.y;
#pragma unroll
    for (int i = 0; i < 4; i++) t[ty + 8 * i][tx] = W[(k0 + ty + 8 * i) * N + n0 + tx];
    __syncthreads();
#pragma unroll
    for (int i = 0; i < 4; i++) Wt[(n0 + ty + 8 * i) * K + k0 + tx] = f2bf(t[tx][ty + 8 * i]);
}

// ---------------- LayerNorm: one block per row of [4096][1024], bf16 out ----------------
__global__ __launch_bounds__(256) void ln_kernel(
    const float* __restrict__ x, const float* __restrict__ w, const float* __restrict__ b,
    short* __restrict__ out) {
    int row = blockIdx.x, tid = threadIdx.x;
    float4 v = ((const float4*)(x + row * C_DIM))[tid];
    float s  = v.x + v.y + v.z + v.w;
    float sq = v.x * v.x + v.y * v.y + v.z * v.z + v.w * v.w;
#pragma unroll
    for (int off = 32; off > 0; off >>= 1) {
        s  += __shfl_down(s, off, 64);
        sq += __shfl_down(sq, off, 64);
    }
    __shared__ float rs[4], rq[4];
    int wv = tid >> 6, ln = tid & 63;
    if (ln == 0) { rs[wv] = s; rq[wv] = sq; }
    __syncthreads();
    s = rs[0] + rs[1] + rs[2] + rs[3];
    sq = rq[0] + rq[1] + rq[2] + rq[3];
    float mean = s * (1.f / C_DIM);
    float rstd = rsqrtf(sq * (1.f / C_DIM) - mean * mean + 1e-5f);
    float4 wv4 = ((const float4*)w)[tid];
    float4 bv4 = ((const float4*)b)[tid];
    s16x4 o;
    o[0] = f2bf((v.x - mean) * rstd * wv4.x + bv4.x);
    o[1] = f2bf((v.y - mean) * rstd * wv4.y + bv4.y);
    o[2] = f2bf((v.z - mean) * rstd * wv4.z + bv4.z);
    o[3] = f2bf((v.w - mean) * rstd * wv4.w + bv4.w);
    *(s16x4*)(out + row * C_DIM + tid * 4) = o;
}

// ---------------- residual + LayerNorm: x1 = x + y (fp32 out), h2 = LN(x1) bf16 ----------------
__global__ __launch_bounds__(256) void resln_kernel(
    const float* __restrict__ x, const float* __restrict__ y,
    const float* __restrict__ w, const float* __restrict__ b,
    float* __restrict__ x1, short* __restrict__ out) {
    int row = blockIdx.x, tid = threadIdx.x;
    float4 vx = ((const float4*)(x + row * C_DIM))[tid];
    float4 vy = ((const float4*)(y + row * C_DIM))[tid];
    float4 v;
    v.x = vx.x + vy.x; v.y = vx.y + vy.y; v.z = vx.z + vy.z; v.w = vx.w + vy.w;
    ((float4*)(x1 + row * C_DIM))[tid] = v;
    float s  = v.x + v.y + v.z + v.w;
    float sq = v.x * v.x + v.y * v.y + v.z * v.z + v.w * v.w;
#pragma unroll
    for (int off = 32; off > 0; off >>= 1) {
        s  += __shfl_down(s, off, 64);
        sq += __shfl_down(sq, off, 64);
    }
    __shared__ float rs[4], rq[4];
    int wv = tid >> 6, ln = tid & 63;
    if (ln == 0) { rs[wv] = s; rq[wv] = sq; }
    __syncthreads();
    s = rs[0] + rs[1] + rs[2] + rs[3];
    sq = rq[0] + rq[1] + rq[2] + rq[3];
    float mean = s * (1.f / C_DIM);
    float rstd = rsqrtf(sq * (1.f / C_DIM) - mean * mean + 1e-5f);
    float4 wv4 = ((const float4*)w)[tid];
    float4 bv4 = ((const float4*)b)[tid];
    s16x4 o;
    o[0] = f2bf((v.x - mean) * rstd * wv4.x + bv4.x);
    o[1] = f2bf((v.y - mean) * rstd * wv4.y + bv4.y);
    o[2] = f2bf((v.z - mean) * rstd * wv4.z + bv4.z);
    o[3] = f2bf((v.w - mean) * rstd * wv4.w + bv4.w);
    *(s16x4*)(out + row * C_DIM + tid * 4) = o;
}

// ---------------- GEMM: C[M=4096,N] = A[M,K](bf16) @ Wt[N,K]^T(bf16) + bias, fused epilogues --------
// 128x128 tile, BK=64, 4 waves (2x2), each wave 64x64 via 4x4 frags of 16x16x32 MFMA.
// LDS XOR-swizzle (byte ^= (row&7)<<4) => conflict-free ds_read_b128 frag reads.
// mode 0: fused QKV (N=3072): q->bf16 qb[B,H,T,D]; k->bf16 kb + fp32 kout; v->fp32 vout + bf16 vT
// mode 1: FC: gelu -> bf16 os0[M,N]
// mode 2: PROJ: + bias + extra(x1) -> fp32 of0[M,N]
__global__ __launch_bounds__(256) void gemm_kernel(
    const short* __restrict__ A, const short* __restrict__ Bt,
    int K, int N, int mode,
    const float* __restrict__ b0, const float* __restrict__ b1, const float* __restrict__ b2,
    short* __restrict__ os0, short* __restrict__ os1, short* __restrict__ os2,
    float* __restrict__ of0, float* __restrict__ of1,
    const float* __restrict__ extra) {
    __shared__ short As[128 * 64];
    __shared__ short Bs[128 * 64];
    int tid = threadIdx.x;
    int wv = tid >> 6, lane = tid & 63, g = lane >> 4, r4 = lane & 15;
    int wr = wv >> 1, wc = wv & 1;
    int m0 = blockIdx.x * 128, n0 = blockIdx.y * 128;

    const f32x4 zero4 = {0.f, 0.f, 0.f, 0.f};
    f32x4 acc[4][4];
#pragma unroll
    for (int i = 0; i < 4; i++)
#pragma unroll
        for (int j = 0; j < 4; j++) acc[i][j] = zero4;

    int rowS[4], colS[4], wo[4];
#pragma unroll
    for (int p = 0; p < 4; p++) {
        int idx = p * 2048 + tid * 8;          // element (short) index in 128x64 tile
        rowS[p] = idx >> 6;
        colS[p] = idx & 63;
        wo[p] = (rowS[p] * 128 + colS[p] * 2) ^ ((rowS[p] & 7) << 4);
    }

    s16x8 rA[4], rB[4];
#pragma unroll
    for (int p = 0; p < 4; p++) {
        rA[p] = *(const s16x8*)&A[(m0 + rowS[p]) * K + colS[p]];
        rB[p] = *(const s16x8*)&Bt[(n0 + rowS[p]) * K + colS[p]];
    }
#pragma unroll
    for (int p = 0; p < 4; p++) {
        *(s16x8*)((char*)As + wo[p]) = rA[p];
        *(s16x8*)((char*)Bs + wo[p]) = rB[p];
    }
    __syncthreads();

    int NT = K >> 6;
    for (int t = 0; t < NT; ++t) {
        if (t + 1 < NT) {
            int kofs = (t + 1) << 6;
#pragma unroll
            for (int p = 0; p < 4; p++) {
                rA[p] = *(const s16x8*)&A[(m0 + rowS[p]) * K + kofs + colS[p]];
                rB[p] = *(const s16x8*)&Bt[(n0 + rowS[p]) * K + kofs + colS[p]];
            }
        }
#pragma unroll
        for (int kk = 0; kk < 2; kk++) {
            s16x8 af[4], bfr[4];
#pragma unroll
            for (int mi = 0; mi < 4; mi++) {
                int row = wr * 64 + mi * 16 + r4;
                af[mi] = *(const s16x8*)((const char*)As +
                          ((row * 128 + kk * 64 + g * 16) ^ ((row & 7) << 4)));
            }
#pragma unroll
            for (int ni = 0; ni < 4; ni++) {
                int row = wc * 64 + ni * 16 + r4;
                bfr[ni] = *(const s16x8*)((const char*)Bs +
                           ((row * 128 + kk * 64 + g * 16) ^ ((row & 7) << 4)));
            }
#pragma unroll
            for (int mi = 0; mi < 4; mi++)
#pragma unroll
                for (int ni = 0; ni < 4; ni++)
                    acc[mi][ni] = __builtin_amdgcn_mfma_f32_16x16x32_bf16(
                        af[mi], bfr[ni], acc[mi][ni], 0, 0, 0);
        }
        __syncthreads();
        if (t + 1 < NT) {
#pragma unroll
            for (int p = 0; p < 4; p++) {
                *(s16x8*)((char*)As + wo[p]) = rA[p];
                *(s16x8*)((char*)Bs + wo[p]) = rB[p];
            }
        }
        __syncthreads();
    }

    // epilogue: D layout col = lane&15, row = 4*(lane>>4)+r  [verified m89/m91]
#pragma unroll
    for (int mi = 0; mi < 4; mi++) {
#pragma unroll
        for (int ni = 0; ni < 4; ni++) {
            int n = n0 + wc * 64 + ni * 16 + r4;
#pragma unroll
            for (int r = 0; r < 4; r++) {
                int m = m0 + wr * 64 + mi * 16 + 4 * g + r;
                float val = acc[mi][ni][r];
                if (mode == 0) {
                    int sel = n >> 10, nn = n & 1023;
                    const float* bp = (sel == 0) ? b0 : ((sel == 1) ? b1 : b2);
                    val += bp[nn];
                    int bb = m >> 11, tt = m & 2047, h = nn >> 6, d = nn & 63;
                    int qi = ((bb * HEADS + h) * T_SEQ + tt) * HD + d;
                    if (sel == 0) {
                        os0[qi] = f2bf(val);
                    } else if (sel == 1) {
                        os1[qi] = f2bf(val);
                        of0[qi] = val;
                    } else {
                        of1[qi] = val;
                        os2[((bb * HEADS + h) * HD + d) * T_SEQ + tt] = f2bf(val);
                    }
                } else if (mode == 1) {
                    val += b0[n];
                    val = 0.5f * val * (1.f + erff(val * 0.70710678118f));  // exact GELU
                    os0[m * N + n] = f2bf(val);
                } else {
                    val += b0[n];
                    of0[m * N + n] = val + extra[m * N + n];
                }
            }
        }
    }
}

// ---------------- causal flash attention ----------------
// grid (T/128, B*H); 4 waves x 32 q-rows. KV tile = 64. K in [T,D] (bf16), V pre-transposed [D,T].
__global__ __launch_bounds__(256) void attn_kernel(
    const short* __restrict__ qb, const short* __restrict__ kb,
    const short* __restrict__ vtb, float* __restrict__ y) {
    __shared__ short Ks[64 * 64];
    __shared__ short Vs[64 * 64];
    __shared__ short Ps[4][32 * 64];
    int qt = blockIdx.x, bh = blockIdx.y;
    int tid = threadIdx.x, w = tid >> 6, lane = tid & 63, g = lane >> 4, r4 = lane & 15;
    int qbase = qt * 128;

    // Q fragments in registers (reused across all s-tiles)
    const short* Qp = qb + (bh * T_SEQ + qbase + w * 32) * HD;
    s16x8 qf[2][2];
#pragma unroll
    for (int mi = 0; mi < 2; mi++)
#pragma unroll
        for (int kk = 0; kk < 2; kk++)
            qf[mi][kk] = *(const s16x8*)&Qp[(mi * 16 + r4) * HD + kk * 32 + g * 8];

    const f32x4 zero4 = {0.f, 0.f, 0.f, 0.f};
    f32x4 yacc[2][4];
    float mrun[2][4], lrun[2][4];
#pragma unroll
    for (int mi = 0; mi < 2; mi++) {
#pragma unroll
        for (int ni = 0; ni < 4; ni++) yacc[mi][ni] = zero4;
#pragma unroll
        for (int r = 0; r < 4; r++) { mrun[mi][r] = -1e30f; lrun[mi][r] = 0.f; }
    }

    int idx0 = tid * 8, idx1 = 2048 + tid * 8;
    int r0 = idx0 >> 6, c0 = idx0 & 63, r1 = idx1 >> 6, c1 = idx1 & 63;
    int wo0 = (r0 * 128 + c0 * 2) ^ ((r0 & 7) << 4);
    int wo1 = (r1 * 128 + c1 * 2) ^ ((r1 & 7) << 4);

    s16x8 kreg0, kreg1, vreg0, vreg1;
    // prologue: stage s-tile 0
    kreg0 = *(const s16x8*)&kb[(bh * T_SEQ + r0) * HD + c0];
    kreg1 = *(const s16x8*)&kb[(bh * T_SEQ + r1) * HD + c1];
    vreg0 = *(const s16x8*)&vtb[(bh * HD + r0) * T_SEQ + c0];
    vreg1 = *(const s16x8*)&vtb[(bh * HD + r1) * T_SEQ + c1];
    *(s16x8*)((char*)Ks + wo0) = kreg0;
    *(s16x8*)((char*)Ks + wo1) = kreg1;
    *(s16x8*)((char*)Vs + wo0) = vreg0;
    *(s16x8*)((char*)Vs + wo1) = vreg1;
    __syncthreads();

    int nst = 2 * qt + 2;
    for (int st = 0; st < nst; ++st) {
        int s0 = st * 64;
        if (st + 1 < nst) {  // prefetch next tile into regs (hidden under compute)
            int s0n = s0 + 64;
            kreg0 = *(const s16x8*)&kb[(bh * T_SEQ + s0n + r0) * HD + c0];
            kreg1 = *(const s16x8*)&kb[(bh * T_SEQ + s0n + r1) * HD + c1];
            vreg0 = *(const s16x8*)&vtb[(bh * HD + r0) * T_SEQ + s0n + c0];
            vreg1 = *(const s16x8*)&vtb[(bh * HD + r1) * T_SEQ + s0n + c1];
        }
        // ---- S = Q K^T
        f32x4 sacc[2][4];
#pragma unroll
        for (int mi = 0; mi < 2; mi++)
#pragma unroll
            for (int sb = 0; sb < 4; sb++) sacc[mi][sb] = zero4;
#pragma unroll
        for (int kk = 0; kk < 2; kk++) {
            s16x8 kf[4];
#pragma unroll
            for (int sb = 0; sb < 4; sb++) {
                int srow = sb * 16 + r4;
                kf[sb] = *(const s16x8*)((const char*)Ks +
                          ((srow * 128 + kk * 64 + g * 16) ^ ((srow & 7) << 4)));
            }
#pragma unroll
            for (int mi = 0; mi < 2; mi++)
#pragma unroll
                for (int sb = 0; sb < 4; sb++)
                    sacc[mi][sb] = __builtin_amdgcn_mfma_f32_16x16x32_bf16(
                        qf[mi][kk], kf[sb], sacc[mi][sb], 0, 0, 0);
        }
        // ---- online softmax (rows live in 16-lane groups)
#pragma unroll
        for (int mi = 0; mi < 2; mi++) {
            float pvv[4][4];
            float mx[4] = {-1e30f, -1e30f, -1e30f, -1e30f};
#pragma unroll
            for (int sb = 0; sb < 4; sb++) {
                int sg = s0 + sb * 16 + r4;
#pragma unroll
                for (int r = 0; r < 4; r++) {
                    int qg = qbase + w * 32 + mi * 16 + 4 * g + r;
                    float valv = sacc[mi][sb][r] * 0.125f;  // 1/sqrt(64)
                    if (sg > qg) valv = -1e30f;             // causal mask
                    pvv[sb][r] = valv;
                    mx[r] = fmaxf(mx[r], valv);
                }
            }
#pragma unroll
            for (int r = 0; r < 4; r++) {
#pragma unroll
                for (int off = 1; off < 16; off <<= 1)
                    mx[r] = fmaxf(mx[r], __shfl_xor(mx[r], off, 64));
            }
#pragma unroll
            for (int r = 0; r < 4; r++) {
                float mnew = fmaxf(mrun[mi][r], mx[r]);
                float alpha = __expf(mrun[mi][r] - mnew);
                mrun[mi][r] = mnew;
                float rsum = 0.f;
#pragma unroll
                for (int sb = 0; sb < 4; sb++) {
                    float p = __expf(pvv[sb][r] - mnew);
                    pvv[sb][r] = p;
                    rsum += p;
                }
#pragma unroll
                for (int off = 1; off < 16; off <<= 1) rsum += __shfl_xor(rsum, off, 64);
                lrun[mi][r] = lrun[mi][r] * alpha + rsum;
#pragma unroll
                for (int ni = 0; ni < 4; ni++) yacc[mi][ni][r] *= alpha;
            }
            // P -> LDS (bf16, swizzled) for the PV A-operand transpose
#pragma unroll
            for (int sb = 0; sb < 4; sb++)
#pragma unroll
                for (int r = 0; r < 4; r++) {
                    int prow = mi * 16 + 4 * g + r, pcol = sb * 16 + r4;
                    *(short*)((char*)&Ps[w][0] +
                              ((prow * 128 + pcol * 2) ^ ((prow & 7) << 4))) = f2bf(pvv[sb][r]);
                }
        }
        __syncthreads();
        // ---- Y += P V
#pragma unroll
        for (int kk = 0; kk < 2; kk++) {
            s16x8 pf[2], vb[4];
#pragma unroll
            for (int mi = 0; mi < 2; mi++) {
                int prow = mi * 16 + r4;
                pf[mi] = *(const s16x8*)((const char*)&Ps[w][0] +
                          ((prow * 128 + kk * 64 + g * 16) ^ ((prow & 7) << 4)));
            }
#pragma unroll
            for (int ni = 0; ni < 4; ni++) {
                int drow = ni * 16 + r4;
                vb[ni] = *(const s16x8*)((const char*)Vs +
                          ((drow * 128 + kk * 64 + g * 16) ^ ((drow & 7) << 4)));
            }
#pragma unroll
            for (int mi = 0; mi < 2; mi++)
#pragma unroll
                for (int ni = 0; ni < 4; ni++)
                    yacc[mi][ni] = __builtin_amdgcn_mfma_f32_16x16x32_bf16(
                        pf[mi], vb[ni], yacc[mi][ni], 0, 0, 0);
        }
        __syncthreads();
        if (st + 1 < nst) {
            *(s16x8*)((char*)Ks + wo0) = kreg0;
            *(s16x8*)((char*)Ks + wo1) = kreg1;
            *(s16x8*)((char*)Vs + wo0) = vreg0;
            *(s16x8*)((char*)Vs + wo1) = vreg1;
        }
        __syncthreads();
    }
    // epilogue: y[b, t, h*64+d] fp32
    int bb = bh >> 4, h = bh & 15;
#pragma unroll
    for (int mi = 0; mi < 2; mi++)
#pragma unroll
        for (int ni = 0; ni < 4; ni++)
#pragma unroll
            for (int r = 0; r < 4; r++) {
                int q = qbase + w * 32 + mi * 16 + 4 * g + r;
                int d = ni * 16 + r4;
                y[(bb * T_SEQ + q) * C_DIM + h * HD + d] = yacc[mi][ni][r] / lrun[mi][r];
            }
}

extern "C" void kernel_launch(void* const* d_in, const int* in_sizes, int n_in,
                              void* d_out, int out_size, void* d_ws, size_t ws_size,
                              hipStream_t stream) {
    (void)in_sizes; (void)n_in; (void)out_size; (void)ws_size;
    const float* x    = (const float*)d_in[0];
    const float* wq   = (const float*)d_in[1];
    const float* bq   = (const float*)d_in[2];
    const float* wk   = (const float*)d_in[3];
    const float* bk   = (const float*)d_in[4];
    const float* wvp  = (const float*)d_in[5];
    const float* bv   = (const float*)d_in[6];
    const float* ln1w = (const float*)d_in[7];
    const float* ln1b = (const float*)d_in[8];
    const float* ln2w = (const float*)d_in[9];
    const float* ln2b = (const float*)d_in[10];
    const float* wfc  = (const float*)d_in[11];
    const float* bfc  = (const float*)d_in[12];
    const float* wpr  = (const float*)d_in[13];
    const float* bpr  = (const float*)d_in[14];

    float* xout = (float*)d_out;                 // [2,2048,1024]
    float* kout = xout + 4194304;                // [2,16,2048,64]
    float* vout = kout + 4194304;                // [2,16,2048,64]

    // workspace layout (bf16 region then fp32 region), ~126 MB total
    short* wqkvt = (short*)d_ws;                 // [3072][1024] bf16 (q rows 0-1023, k, v)
    short* wfct  = wqkvt + 3072 * 1024;          // [4096][1024]
    short* wprt  = wfct + 4096 * 1024;           // [1024][4096]
    short* hb    = wprt + 1024 * 4096;           // LN1 out bf16 [4096][1024]
    short* qb    = hb + 4096 * 1024;             // Q bf16 [B,H,T,D]
    short* kbuf  = qb + 4096 * 1024;             // K bf16 [B,H,T,D]
    short* vtb   = kbuf + 4096 * 1024;           // V bf16 transposed [B,H,D,T]
    short* h2b   = vtb + 4096 * 1024;            // LN2 out bf16
    short* fcb   = h2b + 4096 * 1024;            // gelu(fc) bf16 [4096][4096]
    float* ybuf  = (float*)(fcb + 4096 * 4096);  // attn out fp32 [4096][1024]
    float* x1    = ybuf + 4096 * 1024;           // x + y fp32

    dim3 tb(32, 8);
    transpose_cast_kernel<<<dim3(32, 32),  tb, 0, stream>>>(wq,  wqkvt,                1024, 1024);
    transpose_cast_kernel<<<dim3(32, 32),  tb, 0, stream>>>(wk,  wqkvt + 1024 * 1024,  1024, 1024);
    transpose_cast_kernel<<<dim3(32, 32),  tb, 0, stream>>>(wvp, wqkvt + 2048 * 1024,  1024, 1024);
    transpose_cast_kernel<<<dim3(128, 32), tb, 0, stream>>>(wfc, wfct,                 1024, 4096);
    transpose_cast_kernel<<<dim3(32, 128), tb, 0, stream>>>(wpr, wprt,                 4096, 1024);

    ln_kernel<<<4096, 256, 0, stream>>>(x, ln1w, ln1b, hb);

    // fused QKV GEMM: N = 3072
    gemm_kernel<<<dim3(32, 24), 256, 0, stream>>>(hb, wqkvt, 1024, 3072, 0,
        bq, bk, bv, qb, kbuf, vtb, kout, vout, nullptr);

    attn_kernel<<<dim3(16, 32), 256, 0, stream>>>(qb, kbuf, vtb, ybuf);

    resln_kernel<<<4096, 256, 0, stream>>>(x, ybuf, ln2w, ln2b, x1, h2b);

    // MLP fc + gelu
    gemm_kernel<<<dim3(32, 32), 256, 0, stream>>>(h2b, wfct, 1024, 4096, 1,
        bfc, nullptr, nullptr, fcb, nullptr, nullptr, nullptr, nullptr, nullptr);

    // MLP proj + bias + residual -> x_out
    gemm_kernel<<<dim3(32, 8), 256, 0, stream>>>(fcb, wprt, 4096, 1024, 2,
        bpr, nullptr, nullptr, nullptr, nullptr, nullptr, xout, nullptr, x1);
}